// Round 10
// baseline (358.363 us; speedup 1.0000x reference)
//
#include <hip/hip_runtime.h>
#include <cstddef>

#define NBLK 512

typedef __attribute__((ext_vector_type(8))) short bf16x8;
typedef __attribute__((ext_vector_type(4))) float f32x4;

__device__ __forceinline__ float lrelu(float x) { return x >= 0.f ? x : 0.2f * x; }
__device__ __forceinline__ unsigned short f2bf(float x) {
    unsigned u = __float_as_uint(x);
    u += 0x7FFFu + ((u >> 16) & 1u);
    return (unsigned short)(u >> 16);
}
__device__ __forceinline__ float bf2f(unsigned short u) {
    return __uint_as_float((unsigned)u << 16);
}

// ---------------- sync area (uint indices into sync[]) ----------------
#define SY_CNT 0      // 8 lines: per-XCD registration counters
#define SY_GA  256    // 8 lines: global rendezvous arrivals
#define SY_GR  512    // 16 lines: global rendezvous release
#define SY_XB  1024   // 64 lines: per-XCD barrier arrivals (xcd*8 + (r&7))
#define SY_XR  3072   // 32 lines: per-XCD release (xcd*4 + (r&3))

// Per-XCD fence-free barrier (round-7/8 verified structure, unchanged).
__device__ __forceinline__ void xbar(unsigned* sync, int xcd, int r, unsigned cnt,
                                     unsigned ph, int t) {
    __syncthreads();
    if (t == 0) {
        __hip_atomic_fetch_add(&sync[SY_XB + (xcd * 8 + (r & 7)) * 32], 1u,
                               __ATOMIC_RELAXED, __HIP_MEMORY_SCOPE_AGENT);
        if (r == 0) {
            const unsigned tgt = cnt * ph;
            unsigned s;
            do {
                __builtin_amdgcn_s_sleep(1);
                s = 0;
#pragma unroll
                for (int i = 0; i < 8; ++i)
                    s += __hip_atomic_load(&sync[SY_XB + (xcd * 8 + i) * 32],
                                           __ATOMIC_RELAXED, __HIP_MEMORY_SCOPE_AGENT);
            } while (s < tgt);
#pragma unroll
            for (int g = 0; g < 4; ++g)
                __hip_atomic_store(&sync[SY_XR + (xcd * 4 + g) * 32], ph,
                                   __ATOMIC_RELAXED, __HIP_MEMORY_SCOPE_AGENT);
        } else {
            unsigned* w = &sync[SY_XR + (xcd * 4 + (r & 3)) * 32];
            while (__hip_atomic_load(w, __ATOMIC_RELAXED, __HIP_MEMORY_SCOPE_AGENT) < ph)
                __builtin_amdgcn_s_sleep(8);
        }
    }
    __syncthreads();
}

// W (K x 640 fp32) -> WT (640 x K bf16), one 64-col n-tile, 1024 threads. Idempotent.
__device__ __forceinline__ void wtrans(const float* __restrict__ W,
                                       unsigned short* __restrict__ WT,
                                       int K, int nt, int t) {
    int n = nt * 64 + (t & 63);
    for (int kg = t >> 6; kg < K / 8; kg += 16) {
        bf16x8 v;
#pragma unroll
        for (int e = 0; e < 8; ++e) v[e] = (short)f2bf(W[(size_t)(kg * 8 + e) * 640 + n]);
        *(bf16x8*)&WT[(size_t)n * K + kg * 8] = v;
    }
}

// pack y_bonds -> maskp: one uint (4 items x 5 r-bits) per call. Idempotent.
__device__ __forceinline__ void maskpack(const int* __restrict__ bonds,
                                         unsigned char* __restrict__ maskp, int gt) {
    const int4* p = (const int4*)(bonds + (size_t)gt * 20);
    int4 q0 = p[0], q1 = p[1], q2 = p[2], q3 = p[3], q4 = p[4];
    int v[20] = {q0.x, q0.y, q0.z, q0.w, q1.x, q1.y, q1.z, q1.w,
                 q2.x, q2.y, q2.z, q2.w, q3.x, q3.y, q3.z, q3.w,
                 q4.x, q4.y, q4.z, q4.w};
    unsigned m = 0;
#pragma unroll
    for (int k = 0; k < 4; ++k)
#pragma unroll
        for (int r = 0; r < 5; ++r)
            m |= (v[k * 5 + r] == 1) ? (1u << (k * 8 + r)) : 0u;
    *(unsigned*)&maskp[(size_t)gt * 4] = m;
}

// ---------------------------------------------------------------------------------------
// gemm body: one (mt,nt) tile, virtual 256-thread block (t in [0,256)). Round-7 version
// verbatim (lowest register pressure: VGPR 60).
// ---------------------------------------------------------------------------------------
template <int K, int MODE>
__device__ __forceinline__ void gemm_body(int mt, int nt, int t,
                                          const float* __restrict__ Af32,
                                          const unsigned short* __restrict__ Ab,
                                          const unsigned short* __restrict__ WTg,
                                          const float* __restrict__ bias,
                                          const float* __restrict__ avec,
                                          float* __restrict__ srcp,
                                          float* __restrict__ dstp,
                                          unsigned short* __restrict__ hTf) {
    const int n0 = nt * 64, m0 = mt * 64;
    const int w = t >> 6, lane = t & 63;
    const int colg = lane & 15, rquad = lane >> 4;
    const int m = m0 + w * 16 + colg;
    const int koff = rquad * 8;

    f32x4 acc[4] = {};
#pragma unroll
    for (int kk = 0; kk < K; kk += 32) {
        bf16x8 af;
        size_t off = (size_t)m * K + kk + koff;
        if (MODE == 1) {
            af = *(const bf16x8*)&Ab[off];
        } else {
            float4 q0 = *(const float4*)&Af32[off];
            float4 q1 = *(const float4*)&Af32[off + 4];
            af[0] = (short)f2bf(q0.x); af[1] = (short)f2bf(q0.y);
            af[2] = (short)f2bf(q0.z); af[3] = (short)f2bf(q0.w);
            af[4] = (short)f2bf(q1.x); af[5] = (short)f2bf(q1.y);
            af[6] = (short)f2bf(q1.z); af[7] = (short)f2bf(q1.w);
        }
#pragma unroll
        for (int ct = 0; ct < 4; ++ct) {
            bf16x8 bfv = *(const bf16x8*)&WTg[(size_t)(n0 + ct * 16 + colg) * K + kk + koff];
            acc[ct] = __builtin_amdgcn_mfma_f32_16x16x32_bf16(af, bfv, acc[ct], 0, 0, 0);
        }
    }

    const int r = n0 >> 7, chalf = n0 & 127;
    const int b = m0 >> 8, jb = m0 & 255;
    float val[4][4];
    float ssum[4] = {0.f, 0.f, 0.f, 0.f}, dsum[4] = {0.f, 0.f, 0.f, 0.f};
#pragma unroll
    for (int ct = 0; ct < 4; ++ct) {
        int cg = chalf + ct * 16 + colg;
        float bv = bias[n0 + ct * 16 + colg];
        float asr = avec[r * 256 + cg];
        float ads = avec[r * 256 + 128 + cg];
#pragma unroll
        for (int reg = 0; reg < 4; ++reg) {
            float v = acc[ct][reg] + bv;
            val[ct][reg] = v;
            ssum[reg] += v * asr;
            dsum[reg] += v * ads;
        }
    }
#pragma unroll
    for (int mk = 1; mk < 16; mk <<= 1)
#pragma unroll
        for (int reg = 0; reg < 4; ++reg) {
            ssum[reg] += __shfl_xor(ssum[reg], mk);
            dsum[reg] += __shfl_xor(dsum[reg], mk);
        }
    if (colg == 0) {
        int nhalf = (n0 >> 6) & 1;
#pragma unroll
        for (int reg = 0; reg < 4; ++reg) {
            int row = m0 + w * 16 + rquad * 4 + reg;
            srcp[nhalf * 40960 + row * 5 + r] = ssum[reg];
            dstp[nhalf * 40960 + row * 5 + r] = dsum[reg];
        }
    }
    {
        const int joct = (jb >> 3) + w * 2 + (rquad >> 1);
        const size_t tile = (size_t)((b * 5 + r) * 32 + joct) * 1024;
        const int sub = (rquad & 1) * 4;
#pragma unroll
        for (int ct = 0; ct < 4; ++ct) {
            int c = chalf + ct * 16 + colg;
            uint2 pk;
            pk.x = (unsigned)f2bf(val[ct][0]) | ((unsigned)f2bf(val[ct][1]) << 16);
            pk.y = (unsigned)f2bf(val[ct][2]) | ((unsigned)f2bf(val[ct][3]) << 16);
            *(uint2*)&hTf[tile + (size_t)c * 8 + sub] = pk;
        }
    }
}

// ---------------------------------------------------------------------------------------
// agg body: one (b,itile) unit, 1024 threads (16 waves). P-gen over 1024 threads;
// MFMA 40 steps split across wave pairs (w, w+8): wave w covers c=(w&7)*16+colg,
// s in [(w>>3)*20, +20). Partials combined through LDS (reuses dead Ps region).
// ---------------------------------------------------------------------------------------
template <int FINAL>
__device__ __forceinline__ void agg_body(int b, int itile, int t, unsigned char* SM,
                                         const unsigned short* __restrict__ hTf,
                                         const float* __restrict__ srcp,
                                         const float* __restrict__ dstp,
                                         const unsigned char* __restrict__ maskp,
                                         unsigned short* __restrict__ Ab,
                                         float* __restrict__ poolS,
                                         float* __restrict__ poolM) {
    unsigned short* Ps = (unsigned short*)SM;         // 40960 B
    float* accb = (float*)SM;                         // 16 KB, reuses Ps after MFMA
    float* Ds2l = (float*)(SM + 40960);               // 5120 B
    float* Ss   = (float*)(SM + 46080);               // 320 B
    float* Zw   = (float*)(SM + 46400);               // 1024 B (16 waves x 16)
    float* Zrow = (float*)(SM + 47424);               // 64 B

    const int ib = b * 256 + itile * 16;
    const int w = t >> 6, lane = t & 63;
    const int colg = lane & 15, rquad = lane >> 4;
    const size_t bbase = (size_t)(b * 5) * 32 * 1024;

    if (t < 80) Ss[t] = srcp[(size_t)ib * 5 + t] + srcp[40960 + (size_t)ib * 5 + t];
    for (int idx = t; idx < 1280; idx += 1024) {
        int jl = idx & 255, rr = idx >> 8;
        size_t o = (size_t)(b * 256 + jl) * 5 + rr;
        Ds2l[rr * 256 + jl] = dstp[o] + dstp[40960 + o];
    }
    __syncthreads();

    // P generation: 2560 chunks over 1024 threads (2-3 each); i = t&15, kq = (t>>4)&3
    {
        const int i = t & 15;
        const int kq = (t >> 4) & 3;
        float esum = 0.f;
#pragma unroll
        for (int it = 0; it < 3; ++it) {
            int p = it * 1024 + t;
            if (p < 2560) {
                int s = p >> 6;
                int k0 = s * 32 + kq * 8;
                int rr = k0 >> 8, j0 = k0 & 255;
                uint2 mk8 = *(const uint2*)&maskp[((size_t)(ib + i) << 8) + j0];
                float sv = Ss[i * 5 + rr];
                float4 d0 = *(const float4*)&Ds2l[rr * 256 + j0];
                float4 d1 = *(const float4*)&Ds2l[rr * 256 + j0 + 4];
                float dv[8] = {d0.x, d0.y, d0.z, d0.w, d1.x, d1.y, d1.z, d1.w};
                bf16x8 pv;
#pragma unroll
                for (int e = 0; e < 8; ++e) {
                    unsigned mb = ((e < 4 ? (mk8.x >> (8 * e)) : (mk8.y >> (8 * (e - 4)))) >> rr) & 1u;
                    float vv = lrelu(sv + dv[e]);
                    float ev = mb ? __expf(vv) : 0.f;
                    unsigned short q = f2bf(ev);
                    pv[e] = (short)q;
                    esum += __uint_as_float((unsigned)q << 16);
                }
                *(bf16x8*)&Ps[p * 8] = pv;
            }
        }
        esum += __shfl_xor(esum, 16);
        esum += __shfl_xor(esum, 32);
        if (lane < 16) Zw[w * 16 + (lane & 15)] = esum;
    }
    __syncthreads();
    if (t < 16) {
        float z = 0.f;
#pragma unroll
        for (int ww = 0; ww < 16; ++ww) z += Zw[ww * 16 + t];
        Zrow[t] = 1.f / z;
    }

    // MFMA: wave w -> c-group (w&7), s-half (w>>3); 20 steps, 2 acc chains
    const int c = (w & 7) * 16 + colg;
    const int sbase = (w >> 3) * 20;
    f32x4 acc0 = {}, acc1 = {};
#pragma unroll 4
    for (int q = 0; q < 20; ++q) {
        int s = sbase + q;
        bf16x8 af = *(const bf16x8*)&Ps[(s * 64 + lane) * 8];
        bf16x8 bfv = *(const bf16x8*)&hTf[bbase +
            (size_t)((s >> 3) * 32 + (s & 7) * 4 + rquad) * 1024 + (size_t)c * 8];
        if (q & 1) acc1 = __builtin_amdgcn_mfma_f32_16x16x32_bf16(af, bfv, acc1, 0, 0, 0);
        else       acc0 = __builtin_amdgcn_mfma_f32_16x16x32_bf16(af, bfv, acc0, 0, 0, 0);
    }
    __syncthreads();                                  // all Ps reads done -> reuse as accb
    {
        f32x4 ac;
#pragma unroll
        for (int reg = 0; reg < 4; ++reg) ac[reg] = acc0[reg] + acc1[reg];
        *(f32x4*)&accb[(size_t)(w * 64 + lane) * 4] = ac;
    }
    __syncthreads();
    if (t < 512) {                                    // waves 0..7 finalize (c covered once)
        f32x4 pa = *(const f32x4*)&accb[(size_t)(w * 64 + lane) * 4];
        f32x4 pb = *(const f32x4*)&accb[(size_t)((w + 8) * 64 + lane) * 4];
        const int irow = ib + rquad * 4;
        if (FINAL) {
            float ps = 0.f, pm = -3.4e38f;
#pragma unroll
            for (int reg = 0; reg < 4; ++reg) {
                float v = (pa[reg] + pb[reg]) * Zrow[rquad * 4 + reg];
                ps += v;
                pm = fmaxf(pm, v);
            }
            ps += __shfl_xor(ps, 16);
            ps += __shfl_xor(ps, 32);
            pm = fmaxf(pm, __shfl_xor(pm, 16));
            pm = fmaxf(pm, __shfl_xor(pm, 32));
            if (rquad == 0) {
                poolS[(size_t)(b * 16 + itile) * 128 + c] = ps;
                poolM[(size_t)(b * 16 + itile) * 128 + c] = pm;
            }
        } else {
#pragma unroll
            for (int reg = 0; reg < 4; ++reg) {
                float v = (pa[reg] + pb[reg]) * Zrow[rquad * 4 + reg];
                Ab[(size_t)(irow + reg) * 128 + c] = f2bf(lrelu(v));
            }
        }
    }
}

// ---------------------------------------------------------------------------------------
// Fused MLP tail, one 1024-thread block per b. Quarter q4 computes 4 kc-partials of 80 k
// each; combine + mlp2 + mlp3 as before (fp32 reassociation only).
// ---------------------------------------------------------------------------------------
__device__ __forceinline__ void mlp_fused(int b, int t, unsigned char* SM,
                                          const float* __restrict__ x,
                                          const float* __restrict__ poolS,
                                          const float* __restrict__ poolM,
                                          const float* __restrict__ We1,
                                          const float* __restrict__ be1,
                                          const float* __restrict__ We2,
                                          const float* __restrict__ be2,
                                          const float* __restrict__ We3,
                                          const float* __restrict__ be3,
                                          float* __restrict__ out) {
    float* zs  = (float*)SM;               // 5120 B
    float* p16 = (float*)(SM + 5120);      // 16 x 256 f = 16384 B
    float* z1s = (float*)(SM + 21504);     // 1024 B
    float* s2p = (float*)(SM + 22528);     // 1024 B
    float* z2s = (float*)(SM + 23552);     // 128 B
    __syncthreads();
    for (int k = t; k < 1280; k += 1024) {
        float v;
        if (k < 1024) {
            v = x[(size_t)b * 1024 + k];
        } else if (k < 1152) {
            int f = k - 1024;
            float s = 0.f;
#pragma unroll
            for (int it = 0; it < 16; ++it) s += poolS[(size_t)(b * 16 + it) * 128 + f];
            v = s * (1.f / 256.f);
        } else {
            int f = k - 1152;
            float mx = -3.4e38f;
#pragma unroll
            for (int it = 0; it < 16; ++it) mx = fmaxf(mx, poolM[(size_t)(b * 16 + it) * 128 + f]);
            v = mx;
        }
        zs[k] = v;
    }
    __syncthreads();
    {
        const int o = t & 255, q4 = t >> 8;
#pragma unroll
        for (int j = 0; j < 4; ++j) {
            int kc = q4 * 4 + j;
            float s = 0.f;
#pragma unroll 8
            for (int kk = 0; kk < 80; ++kk)
                s += zs[kc * 80 + kk] * We1[(size_t)(kc * 80 + kk) * 256 + o];
            p16[kc * 256 + o] = s;
        }
    }
    __syncthreads();
    if (t < 256) {
        float s = be1[t];
#pragma unroll
        for (int kc = 0; kc < 16; ++kc) s += p16[kc * 256 + t];
        z1s[t] = lrelu(s);
    }
    __syncthreads();
    if (t < 256) {
        int oo = t & 31, g = t >> 5;
        float p = 0.f;
#pragma unroll
        for (int k = 0; k < 32; ++k) p += z1s[g * 32 + k] * We2[(g * 32 + k) * 32 + oo];
        s2p[g * 32 + oo] = p;
    }
    __syncthreads();
    if (t < 32) {
        float s2 = be2[t];
#pragma unroll
        for (int g = 0; g < 8; ++g) s2 += s2p[g * 32 + t];
        z2s[t] = lrelu(s2);
    }
    __syncthreads();
    if (t == 0) {
        float s3 = be3[0];
#pragma unroll
        for (int k = 0; k < 32; ++k) s3 += z2s[k] * We3[k];
        out[b] = s3;
    }
}

// ---------------- workspace layout ----------------
constexpr size_t O_MASK  = 0;                            // 2,097,152
constexpr size_t O_SRC   = 2097152;  constexpr size_t SRC_SZ = 327680;   // x3
constexpr size_t O_DST   = O_SRC + 3 * SRC_SZ;                           // x3
constexpr size_t O_AB    = O_DST + 3 * SRC_SZ;  constexpr size_t AB_SZ = 2097152;  // x2
constexpr size_t O_HT    = O_AB + 2 * AB_SZ;    constexpr size_t HT_SZ = 10485760; // x3
constexpr size_t O_WTX   = O_HT + 3 * HT_SZ;    constexpr size_t WTX_SZ = 409600;  // x8
constexpr size_t O_POOLS = O_WTX + 8 * WTX_SZ;
constexpr size_t O_POOLM = O_POOLS + 262144;
constexpr size_t O_SYNC  = O_POOLM + 262144;             // 16,384 B zeroed per iter

// =======================================================================================
// XCD-closed persistent kernel: 512 blocks x 1024 threads (2 blocks/CU x 16 waves =
// 32 waves/CU = 100% occupancy; __launch_bounds__(1024,8) caps VGPR at 64 so the
// 2-blocks/CU co-residency needed by the sync is compiler-guaranteed).
// Same phase/sync structure as rounds 7-8 (verified).
// =======================================================================================
__global__ __launch_bounds__(1024, 8) void k_mega(
    const float* __restrict__ x, const float* __restrict__ y_atoms,
    const int* __restrict__ bonds,
    const float* __restrict__ W1, const float* __restrict__ b1, const float* __restrict__ a1,
    const float* __restrict__ W2, const float* __restrict__ b2, const float* __restrict__ a2,
    const float* __restrict__ W3, const float* __restrict__ b3, const float* __restrict__ a3,
    const float* __restrict__ We1, const float* __restrict__ be1,
    const float* __restrict__ We2, const float* __restrict__ be2,
    const float* __restrict__ We3, const float* __restrict__ be3,
    char* __restrict__ ws, float* __restrict__ out) {
    __shared__ __align__(16) unsigned char SM[47488];
    __shared__ unsigned s_nfo[3];
    const int rb = blockIdx.x;
    const int t = threadIdx.x;
    const int q4 = t >> 8, t4 = t & 255;

    unsigned char* maskp = (unsigned char*)(ws + O_MASK);
    unsigned* sync = (unsigned*)(ws + O_SYNC);
    float* poolS = (float*)(ws + O_POOLS);
    float* poolM = (float*)(ws + O_POOLM);

    // ---- registration ----
    if (t == 0) {
        unsigned xr;
        asm volatile("s_getreg_b32 %0, hwreg(HW_REG_XCC_ID)" : "=s"(xr));
        xr &= 7u;
        unsigned rk = __hip_atomic_fetch_add(&sync[SY_CNT + xr * 32], 1u,
                                             __ATOMIC_RELAXED, __HIP_MEMORY_SCOPE_AGENT);
        s_nfo[0] = xr;
        s_nfo[1] = rk;
    }
    __syncthreads();
    const int xcd = (int)s_nfo[0];
    const int r0 = (int)s_nfo[1];

    unsigned short* WT1x = (unsigned short*)(ws + O_WTX + (size_t)xcd * WTX_SZ);
    unsigned short* WT2x = WT1x + 40960;
    unsigned short* WT3x = WT2x + 81920;

    // ---- pre-rendezvous opportunistic prep (idempotent; validated via cnt) ----
    if (r0 < 10)      wtrans(W1, WT1x, 64, r0, t);
    else if (r0 < 20) wtrans(W2, WT2x, 128, r0 - 10, t);
    else if (r0 < 30) wtrans(W3, WT3x, 128, r0 - 20, t);
    {
        unsigned u = (unsigned)r0 * 1024u + (unsigned)t;
        if (u < 65536u) {
            int b = xcd + (int)(u >> 14) * 8;
            maskpack(bonds, maskp, b * 16384 + (int)(u & 16383u));
        }
    }
    __syncthreads();                                  // drain prep stores to own-XCD L2

    // ---- global rendezvous (control-only; doubles as prep barrier) ----
    if (t == 0) {
        __hip_atomic_fetch_add(&sync[SY_GA + (rb & 7) * 32], 1u,
                               __ATOMIC_RELAXED, __HIP_MEMORY_SCOPE_AGENT);
        if (rb == 0) {
            unsigned s;
            do {
                __builtin_amdgcn_s_sleep(1);
                s = 0;
#pragma unroll
                for (int i = 0; i < 8; ++i)
                    s += __hip_atomic_load(&sync[SY_GA + i * 32],
                                           __ATOMIC_RELAXED, __HIP_MEMORY_SCOPE_AGENT);
            } while (s < NBLK);
#pragma unroll
            for (int g = 0; g < 16; ++g)
                __hip_atomic_store(&sync[SY_GR + g * 32], 1u,
                                   __ATOMIC_RELAXED, __HIP_MEMORY_SCOPE_AGENT);
        } else {
            unsigned* w = &sync[SY_GR + (rb >> 5) * 32];
            while (__hip_atomic_load(w, __ATOMIC_RELAXED, __HIP_MEMORY_SCOPE_AGENT) < 1u)
                __builtin_amdgcn_s_sleep(8);
        }
        s_nfo[2] = __hip_atomic_load(&sync[SY_CNT + xcd * 32],
                                     __ATOMIC_RELAXED, __HIP_MEMORY_SCOPE_AGENT);
    }
    __syncthreads();
    const unsigned cnt = s_nfo[2];

    float* src0 = (float*)(ws + O_SRC);
    float* src1 = (float*)(ws + O_SRC + SRC_SZ);
    float* src2 = (float*)(ws + O_SRC + 2 * SRC_SZ);
    float* dst0 = (float*)(ws + O_DST);
    float* dst1 = (float*)(ws + O_DST + SRC_SZ);
    float* dst2 = (float*)(ws + O_DST + 2 * SRC_SZ);
    unsigned short* Ab0 = (unsigned short*)(ws + O_AB);
    unsigned short* Ab1 = (unsigned short*)(ws + O_AB + AB_SZ);
    unsigned short* hT0 = (unsigned short*)(ws + O_HT);
    unsigned short* hT1 = (unsigned short*)(ws + O_HT + HT_SZ);
    unsigned short* hT2 = (unsigned short*)(ws + O_HT + 2 * HT_SZ);

    // ---- P1: [rare fallback: full redundant prep] + gemm1 (4 quarters/block) ----
    if (cnt != 64u) {
        for (int u = 0; u < 10; ++u) wtrans(W1, WT1x, 64, u, t);
        for (int u = 0; u < 10; ++u) wtrans(W2, WT2x, 128, u, t);
        for (int u = 0; u < 10; ++u) wtrans(W3, WT3x, 128, u, t);
        __syncthreads();
        for (unsigned u = t; u < 65536u; u += 1024u) {
            int b = xcd + (int)(u >> 14) * 8;
            maskpack(bonds, maskp, b * 16384 + (int)(u & 16383u));
        }
    }
    for (int u = (int)cnt * q4 + r0; u < 160; u += 4 * (int)cnt) {
        int b = xcd + (u & 3) * 8;
        int mt = b * 4 + ((u >> 2) & 3), nt = u >> 4;
        gemm_body<64, 0>(mt, nt, t4, y_atoms, nullptr, WT1x, b1, a1, src0, dst0, hT0);
    }
    xbar(sync, xcd, r0, cnt, 1, t);

    // ---- P2: agg1 ----
    for (int u = r0; u < 64; u += (int)cnt)
        agg_body<0>(xcd + (u & 3) * 8, u >> 2, t, SM, hT0, src0, dst0, maskp,
                    Ab0, nullptr, nullptr);
    xbar(sync, xcd, r0, cnt, 2, t);

    // ---- P3: gemm2 ----
    for (int u = (int)cnt * q4 + r0; u < 160; u += 4 * (int)cnt) {
        int b = xcd + (u & 3) * 8;
        int mt = b * 4 + ((u >> 2) & 3), nt = u >> 4;
        gemm_body<128, 1>(mt, nt, t4, nullptr, Ab0, WT2x, b2, a2, src1, dst1, hT1);
    }
    xbar(sync, xcd, r0, cnt, 3, t);

    // ---- P4: agg2 ----
    for (int u = r0; u < 64; u += (int)cnt)
        agg_body<0>(xcd + (u & 3) * 8, u >> 2, t, SM, hT1, src1, dst1, maskp,
                    Ab1, nullptr, nullptr);
    xbar(sync, xcd, r0, cnt, 4, t);

    // ---- P5: gemm3 ----
    for (int u = (int)cnt * q4 + r0; u < 160; u += 4 * (int)cnt) {
        int b = xcd + (u & 3) * 8;
        int mt = b * 4 + ((u >> 2) & 3), nt = u >> 4;
        gemm_body<128, 1>(mt, nt, t4, nullptr, Ab1, WT3x, b3, a3, src2, dst2, hT2);
    }
    xbar(sync, xcd, r0, cnt, 5, t);

    // ---- P6: agg3 + pooling ----
    for (int u = r0; u < 64; u += (int)cnt)
        agg_body<1>(xcd + (u & 3) * 8, u >> 2, t, SM, hT2, src2, dst2, maskp,
                    nullptr, poolS, poolM);
    xbar(sync, xcd, r0, cnt, 6, t);

    // ---- P7: fused MLP (one block per b; others exit) ----
    for (int u = r0; u < 4; u += (int)cnt)
        mlp_fused(xcd + u * 8, t, SM, x, poolS, poolM, We1, be1, We2, be2, We3, be3, out);
}

extern "C" void kernel_launch(void* const* d_in, const int* in_sizes, int n_in,
                              void* d_out, int out_size, void* d_ws, size_t ws_size,
                              hipStream_t stream) {
    const float* x       = (const float*)d_in[0];
    const float* y_atoms = (const float*)d_in[1];
    const int*   y_bonds = (const int*)d_in[2];
    const float* W1 = (const float*)d_in[3];
    const float* b1 = (const float*)d_in[4];
    const float* a1 = (const float*)d_in[5];
    const float* W2 = (const float*)d_in[6];
    const float* b2 = (const float*)d_in[7];
    const float* a2 = (const float*)d_in[8];
    const float* W3 = (const float*)d_in[9];
    const float* b3 = (const float*)d_in[10];
    const float* a3 = (const float*)d_in[11];
    const float* We1 = (const float*)d_in[12];
    const float* be1 = (const float*)d_in[13];
    const float* We2 = (const float*)d_in[14];
    const float* be2 = (const float*)d_in[15];
    const float* We3 = (const float*)d_in[16];
    const float* be3 = (const float*)d_in[17];
    float* out = (float*)d_out;
    char* ws = (char*)d_ws;

    hipMemsetAsync(ws + O_SYNC, 0, 16384, stream);
    k_mega<<<NBLK, 1024, 0, stream>>>(
        x, y_atoms, y_bonds, W1, b1, a1, W2, b2, a2, W3, b3, a3,
        We1, be1, We2, be2, We3, be3, ws, out);
}

// Round 11
// 233.457 us; speedup vs baseline: 1.5350x; 1.5350x over previous
//
#include <hip/hip_runtime.h>
#include <cstddef>

typedef __attribute__((ext_vector_type(8))) short bf16x8;
typedef __attribute__((ext_vector_type(4))) float f32x4;

__device__ __forceinline__ float lrelu(float x) { return x >= 0.f ? x : 0.2f * x; }
// RNE float -> bf16
__device__ __forceinline__ unsigned short f2bf(float x) {
    unsigned u = __float_as_uint(x);
    u += 0x7FFFu + ((u >> 16) & 1u);
    return (unsigned short)(u >> 16);
}

// =======================================================================================
// k_prepw: WT1 only (the single dependency of gemm1). 10 blocks x 256 threads.
// W1 (64 x 640 fp32) -> WT1 (640 x 64 bf16).
// =======================================================================================
__global__ __launch_bounds__(256) void k_prepw(const float* __restrict__ W1,
                                               unsigned short* __restrict__ WT1) {
    const int nt = blockIdx.x, t = threadIdx.x;
    const int n = nt * 64 + (t & 63);
    for (int kg = t >> 6; kg < 8; kg += 4) {
        bf16x8 v;
#pragma unroll
        for (int e = 0; e < 8; ++e) v[e] = (short)f2bf(W1[(size_t)(kg * 8 + e) * 640 + n]);
        *(bf16x8*)&WT1[(size_t)n * 64 + kg * 8] = v;
    }
}

// =======================================================================================
// gemm_h: h = A(8192 x K) @ W(K x 640) + bias, MFMA bf16 (fp32 accum). Round-4 verbatim.
// MODE 0: A = fp32 Af32 (layer 1). MODE 1: A = final bf16 Ab written by k_agg.
// EXTRA=1 (layer-1 launch only): blocks >= 1280 do maskpack (2048 blocks) and WT2/WT3
// transposes (20 blocks) — outputs consumed only by LATER nodes (agg1 / gemm2-3), so
// stream order guarantees completion+coherence; their HBM time overlaps gemm1 compute.
// gemm blocks (l < 1280): XCD-affinity swizzle, XCD(mt)=mt/16=b/4 (round-4 verified).
// =======================================================================================
template <int K, int MODE, int EXTRA>
__global__ __launch_bounds__(256) void k_gemm_h(const float* __restrict__ Af32,
                                                const unsigned short* __restrict__ Ab,
                                                const unsigned short* __restrict__ WTg,
                                                const float* __restrict__ bias,
                                                const float* __restrict__ avec,
                                                float* __restrict__ srcp,
                                                float* __restrict__ dstp,
                                                unsigned short* __restrict__ hTf,
                                                const int* __restrict__ bonds,
                                                unsigned char* __restrict__ maskp,
                                                const float* __restrict__ W2,
                                                const float* __restrict__ W3,
                                                unsigned short* __restrict__ WT2,
                                                unsigned short* __restrict__ WT3) {
    const int t = threadIdx.x;
    const int l = blockIdx.x;
    if (EXTRA && l >= 1280) {
        int e = l - 1280;
        if (e < 2048) {
            // mask pack: 4 items (one uint) per thread — round-4 k_prep verbatim
            int gt = e * 256 + t;
            const int4* p = (const int4*)(bonds + (size_t)gt * 20);
            int4 q0 = p[0], q1 = p[1], q2 = p[2], q3 = p[3], q4 = p[4];
            int v[20] = {q0.x, q0.y, q0.z, q0.w, q1.x, q1.y, q1.z, q1.w,
                         q2.x, q2.y, q2.z, q2.w, q3.x, q3.y, q3.z, q3.w,
                         q4.x, q4.y, q4.z, q4.w};
            unsigned m = 0;
#pragma unroll
            for (int k = 0; k < 4; ++k)
#pragma unroll
                for (int r = 0; r < 5; ++r)
                    m |= (v[k * 5 + r] == 1) ? (1u << (k * 8 + r)) : 0u;
            *(unsigned*)&maskp[(size_t)gt * 4] = m;
        } else {
            // WT2 / WT3 transpose (K=128), 20 blocks — round-4 k_prep verbatim
            int e2 = e - 2048;
            const float* W = (e2 < 10) ? W2 : W3;
            unsigned short* WT = (e2 < 10) ? WT2 : WT3;
            int nt = (e2 < 10) ? e2 : e2 - 10;
            int n = nt * 64 + (t & 63);
            for (int kg = t >> 6; kg < 16; kg += 4) {
                bf16x8 v;
#pragma unroll
                for (int ee = 0; ee < 8; ++ee)
                    v[ee] = (short)f2bf(W[(size_t)(kg * 8 + ee) * 640 + n]);
                *(bf16x8*)&WT[(size_t)n * 128 + kg * 8] = v;
            }
        }
        return;
    }
    // bijective swizzle: l = nt*128 + (mt&15)*8 + (mt>>4)
    const int mt = (l & 7) * 16 + ((l >> 3) & 15);   // [0,128)
    const int nt = l >> 7;                            // [0,10)
    const int n0 = nt * 64, m0 = mt * 64;
    const int w = t >> 6, lane = t & 63;
    const int colg = lane & 15, rquad = lane >> 4;
    const int m = m0 + w * 16 + colg;
    const int koff = rquad * 8;

    f32x4 acc[4] = {};
#pragma unroll
    for (int kk = 0; kk < K; kk += 32) {
        bf16x8 af;
        size_t off = (size_t)m * K + kk + koff;
        if (MODE == 1) {
            af = *(const bf16x8*)&Ab[off];
        } else {
            float4 q0 = *(const float4*)&Af32[off];
            float4 q1 = *(const float4*)&Af32[off + 4];
            af[0] = (short)f2bf(q0.x); af[1] = (short)f2bf(q0.y);
            af[2] = (short)f2bf(q0.z); af[3] = (short)f2bf(q0.w);
            af[4] = (short)f2bf(q1.x); af[5] = (short)f2bf(q1.y);
            af[6] = (short)f2bf(q1.z); af[7] = (short)f2bf(q1.w);
        }
#pragma unroll
        for (int ct = 0; ct < 4; ++ct) {
            bf16x8 bfv = *(const bf16x8*)&WTg[(size_t)(n0 + ct * 16 + colg) * K + kk + koff];
            acc[ct] = __builtin_amdgcn_mfma_f32_16x16x32_bf16(af, bfv, acc[ct], 0, 0, 0);
        }
    }

    const int r = n0 >> 7, chalf = n0 & 127;
    const int b = m0 >> 8, jb = m0 & 255;
    float val[4][4];
    float ssum[4] = {0.f, 0.f, 0.f, 0.f}, dsum[4] = {0.f, 0.f, 0.f, 0.f};
#pragma unroll
    for (int ct = 0; ct < 4; ++ct) {
        int cg = chalf + ct * 16 + colg;
        float bv = bias[n0 + ct * 16 + colg];
        float asr = avec[r * 256 + cg];
        float ads = avec[r * 256 + 128 + cg];
#pragma unroll
        for (int reg = 0; reg < 4; ++reg) {
            float v = acc[ct][reg] + bv;
            val[ct][reg] = v;
            ssum[reg] += v * asr;
            dsum[reg] += v * ads;
        }
    }
#pragma unroll
    for (int mk = 1; mk < 16; mk <<= 1)
#pragma unroll
        for (int reg = 0; reg < 4; ++reg) {
            ssum[reg] += __shfl_xor(ssum[reg], mk);
            dsum[reg] += __shfl_xor(dsum[reg], mk);
        }
    if (colg == 0) {
        int nhalf = (n0 >> 6) & 1;
#pragma unroll
        for (int reg = 0; reg < 4; ++reg) {
            int row = m0 + w * 16 + rquad * 4 + reg;
            srcp[nhalf * 40960 + row * 5 + r] = ssum[reg];
            dstp[nhalf * 40960 + row * 5 + r] = dsum[reg];
        }
    }
    {
        const int joct = (jb >> 3) + w * 2 + (rquad >> 1);
        const size_t tile = (size_t)((b * 5 + r) * 32 + joct) * 1024;
        const int sub = (rquad & 1) * 4;
#pragma unroll
        for (int ct = 0; ct < 4; ++ct) {
            int c = chalf + ct * 16 + colg;
            uint2 pk;
            pk.x = (unsigned)f2bf(val[ct][0]) | ((unsigned)f2bf(val[ct][1]) << 16);
            pk.y = (unsigned)f2bf(val[ct][2]) | ((unsigned)f2bf(val[ct][3]) << 16);
            *(uint2*)&hTf[tile + (size_t)c * 8 + sub] = pk;
        }
    }
}

// =======================================================================================
// k_agg: round-4 verbatim. 1-D grid of 512, 512 threads, XCD-affinity swizzle.
// FINAL=0: Ab = bf16(lrelu(agg/Z)); FINAL=1: per-block pooled partials (h3 never stored).
// =======================================================================================
template <int FINAL>
__global__ __launch_bounds__(512, 4) void k_agg(const unsigned short* __restrict__ hTf,
                                                const float* __restrict__ srcp,
                                                const float* __restrict__ dstp,
                                                const unsigned char* __restrict__ maskp,
                                                unsigned short* __restrict__ Ab,
                                                float* __restrict__ poolS,
                                                float* __restrict__ poolM) {
    __shared__ __align__(16) unsigned short Ps[20480];   // 16 i x 1280 k bf16 = 40 KB
    __shared__ __align__(16) float Ds2l[1280];
    __shared__ float Ss[80], Zw[128], Zrow[16];
    const int t = threadIdx.x;
    const int l = blockIdx.x;
    const int b = (l & 7) * 4 + ((l >> 3) & 3);       // [0,32), XCD(b)=b/4
    const int itile = l >> 5;                          // [0,16)
    const int ib = b * 256 + itile * 16;
    const int w = t >> 6, lane = t & 63;
    const int colg = lane & 15, rquad = lane >> 4;
    const int c = w * 16 + colg;
    const size_t bbase = (size_t)(b * 5) * 32 * 1024;

    if (t < 80) Ss[t] = srcp[(size_t)ib * 5 + t] + srcp[40960 + (size_t)ib * 5 + t];
    for (int idx = t; idx < 1280; idx += 512) {
        int jl = idx & 255, rr = idx >> 8;
        size_t o = (size_t)(b * 256 + jl) * 5 + rr;
        Ds2l[rr * 256 + jl] = dstp[o] + dstp[40960 + o];
    }
    bf16x8 pre[4];
#pragma unroll
    for (int s = 0; s < 4; ++s)
        pre[s] = *(const bf16x8*)&hTf[bbase + (size_t)(s * 4 + rquad) * 1024 + (size_t)c * 8];
    __syncthreads();

    {
        const int i = t & 15;
        const int kq = (t >> 4) & 3;
        float esum = 0.f;
#pragma unroll
        for (int it = 0; it < 5; ++it) {
            int p = it * 512 + t;
            int s = p >> 6;
            int k0 = s * 32 + kq * 8;
            int rr = k0 >> 8, j0 = k0 & 255;
            uint2 mk8 = *(const uint2*)&maskp[((size_t)(ib + i) << 8) + j0];
            float sv = Ss[i * 5 + rr];
            float4 d0 = *(const float4*)&Ds2l[rr * 256 + j0];
            float4 d1 = *(const float4*)&Ds2l[rr * 256 + j0 + 4];
            float dv[8] = {d0.x, d0.y, d0.z, d0.w, d1.x, d1.y, d1.z, d1.w};
            bf16x8 pv;
#pragma unroll
            for (int e = 0; e < 8; ++e) {
                unsigned mb = ((e < 4 ? (mk8.x >> (8 * e)) : (mk8.y >> (8 * (e - 4)))) >> rr) & 1u;
                float vv = lrelu(sv + dv[e]);
                float ev = mb ? __expf(vv) : 0.f;
                unsigned short q = f2bf(ev);
                pv[e] = (short)q;
                esum += __uint_as_float((unsigned)q << 16);
            }
            *(bf16x8*)&Ps[p * 8] = pv;
        }
        esum += __shfl_xor(esum, 16);
        esum += __shfl_xor(esum, 32);
        if (lane < 16) Zw[w * 16 + (lane & 15)] = esum;
    }
    __syncthreads();
    if (t < 16) {
        float z = 0.f;
#pragma unroll
        for (int ww = 0; ww < 8; ++ww) z += Zw[ww * 16 + t];
        Zrow[t] = 1.f / z;
    }

    f32x4 acc0 = {}, acc1 = {};
#pragma unroll
    for (int s = 0; s < 8; ++s) {
        bf16x8 af = *(const bf16x8*)&Ps[(s * 64 + lane) * 8];
        bf16x8 bfv;
        if (s < 4) bfv = pre[s];
        else bfv = *(const bf16x8*)&hTf[bbase + (size_t)((s & 7) * 4 + rquad) * 1024 + (size_t)c * 8];
        if (s & 1) acc1 = __builtin_amdgcn_mfma_f32_16x16x32_bf16(af, bfv, acc1, 0, 0, 0);
        else       acc0 = __builtin_amdgcn_mfma_f32_16x16x32_bf16(af, bfv, acc0, 0, 0, 0);
    }
#pragma unroll 8
    for (int s = 8; s < 40; ++s) {
        bf16x8 af = *(const bf16x8*)&Ps[(s * 64 + lane) * 8];
        bf16x8 bfv = *(const bf16x8*)&hTf[bbase +
            (size_t)((s >> 3) * 32 + (s & 7) * 4 + rquad) * 1024 + (size_t)c * 8];
        if (s & 1) acc1 = __builtin_amdgcn_mfma_f32_16x16x32_bf16(af, bfv, acc1, 0, 0, 0);
        else       acc0 = __builtin_amdgcn_mfma_f32_16x16x32_bf16(af, bfv, acc0, 0, 0, 0);
    }
    __syncthreads();
    const int irow = ib + rquad * 4;
    if (FINAL) {
        float ps = 0.f, pm = -3.4e38f;
#pragma unroll
        for (int reg = 0; reg < 4; ++reg) {
            float v = (acc0[reg] + acc1[reg]) * Zrow[rquad * 4 + reg];
            ps += v;
            pm = fmaxf(pm, v);
        }
        ps += __shfl_xor(ps, 16);
        ps += __shfl_xor(ps, 32);
        pm = fmaxf(pm, __shfl_xor(pm, 16));
        pm = fmaxf(pm, __shfl_xor(pm, 32));
        if (rquad == 0) {
            poolS[(size_t)(b * 16 + itile) * 128 + c] = ps;
            poolM[(size_t)(b * 16 + itile) * 128 + c] = pm;
        }
    } else {
#pragma unroll
        for (int reg = 0; reg < 4; ++reg) {
            float v = (acc0[reg] + acc1[reg]) * Zrow[rquad * 4 + reg];
            Ab[(size_t)(irow + reg) * 128 + c] = f2bf(lrelu(v));
        }
    }
}

// =======================================================================================
// k_tail: fused MLP head, one block per b (32 blocks x 256 threads).
// z = [x | mean | max] in LDS; z1[o=t] = lrelu(be1 + sum_k z[k]*We1[k][t]) (We1 is
// 1.31 MB -> L2-resident across the 32 blocks); mlp2 (k-split 8x32); mlp3.
// =======================================================================================
__global__ __launch_bounds__(256) void k_tail(const float* __restrict__ x,
                                              const float* __restrict__ poolS,
                                              const float* __restrict__ poolM,
                                              const float* __restrict__ We1,
                                              const float* __restrict__ be1,
                                              const float* __restrict__ We2,
                                              const float* __restrict__ be2,
                                              const float* __restrict__ We3,
                                              const float* __restrict__ be3,
                                              float* __restrict__ out) {
    __shared__ float zs[1280];
    __shared__ float z1s[256];
    __shared__ float s2p[8][32];
    __shared__ float z2s[32];
    const int b = blockIdx.x, t = threadIdx.x;
    for (int k = t; k < 1024; k += 256) zs[k] = x[(size_t)b * 1024 + k];
    if (t < 128) {
        float s = 0.f;
#pragma unroll
        for (int it = 0; it < 16; ++it) s += poolS[(size_t)(b * 16 + it) * 128 + t];
        zs[1024 + t] = s * (1.f / 256.f);
    } else {
        int f = t - 128;
        float mx = -3.4e38f;
#pragma unroll
        for (int it = 0; it < 16; ++it) mx = fmaxf(mx, poolM[(size_t)(b * 16 + it) * 128 + f]);
        zs[1152 + f] = mx;
    }
    __syncthreads();
    {
        float s = be1[t];
#pragma unroll 8
        for (int k = 0; k < 1280; ++k) s += zs[k] * We1[(size_t)k * 256 + t];
        z1s[t] = lrelu(s);
    }
    __syncthreads();
    {
        int o = t & 31, g = t >> 5;
        float p = 0.f;
#pragma unroll
        for (int k = 0; k < 32; ++k) p += z1s[g * 32 + k] * We2[(g * 32 + k) * 32 + o];
        s2p[g][o] = p;
    }
    __syncthreads();
    if (t < 32) {
        float s2 = be2[t];
#pragma unroll
        for (int g = 0; g < 8; ++g) s2 += s2p[g][t];
        z2s[t] = lrelu(s2);
    }
    __syncthreads();
    if (t == 0) {
        float s3 = be3[0];
#pragma unroll
        for (int k = 0; k < 32; ++k) s3 += z2s[k] * We3[k];
        out[b] = s3;
    }
}

// ---------------- workspace layout (round-4 verbatim, z1p dropped) ----------------
constexpr size_t O_MASK  = 0;                           // 2,097,152
constexpr size_t O_SRCP  = 2097152;                     // 2 x 40960 floats
constexpr size_t O_DSTP  = O_SRCP + 2ull * 40960 * 4;
constexpr size_t O_AB    = O_DSTP + 2ull * 40960 * 4;   // 8192 x 128 bf16 = 2 MB
constexpr size_t O_HT    = O_AB + 2097152;              // 10.5 MB
constexpr size_t O_WT1   = O_HT + 5242880ull * 2;
constexpr size_t O_WT2   = O_WT1 + 640ull * 64 * 2;
constexpr size_t O_WT3   = O_WT2 + 640ull * 128 * 2;
constexpr size_t O_POOLS = O_WT3 + 640ull * 128 * 2;    // 32 x 16 x 128 fp32
constexpr size_t O_POOLM = O_POOLS + 32ull * 16 * 128 * 4;

extern "C" void kernel_launch(void* const* d_in, const int* in_sizes, int n_in,
                              void* d_out, int out_size, void* d_ws, size_t ws_size,
                              hipStream_t stream) {
    const float* x       = (const float*)d_in[0];
    const float* y_atoms = (const float*)d_in[1];
    const int*   y_bonds = (const int*)d_in[2];
    const float* W1 = (const float*)d_in[3];
    const float* b1 = (const float*)d_in[4];
    const float* a1 = (const float*)d_in[5];
    const float* W2 = (const float*)d_in[6];
    const float* b2 = (const float*)d_in[7];
    const float* a2 = (const float*)d_in[8];
    const float* W3 = (const float*)d_in[9];
    const float* b3 = (const float*)d_in[10];
    const float* a3 = (const float*)d_in[11];
    const float* We1 = (const float*)d_in[12];
    const float* be1 = (const float*)d_in[13];
    const float* We2 = (const float*)d_in[14];
    const float* be2 = (const float*)d_in[15];
    const float* We3 = (const float*)d_in[16];
    const float* be3 = (const float*)d_in[17];
    float* out = (float*)d_out;

    char* ws = (char*)d_ws;
    unsigned char* maskp = (unsigned char*)(ws + O_MASK);
    float* srcp = (float*)(ws + O_SRCP);
    float* dstp = (float*)(ws + O_DSTP);
    unsigned short* Ab = (unsigned short*)(ws + O_AB);
    unsigned short* hTf = (unsigned short*)(ws + O_HT);
    unsigned short* WT1 = (unsigned short*)(ws + O_WT1);
    unsigned short* WT2 = (unsigned short*)(ws + O_WT2);
    unsigned short* WT3 = (unsigned short*)(ws + O_WT3);
    float* poolS = (float*)(ws + O_POOLS);
    float* poolM = (float*)(ws + O_POOLM);

    dim3 blk(256);

    // node 1: WT1 only (gemm1's sole dependency)
    k_prepw<<<10, blk, 0, stream>>>(W1, WT1);

    // node 2: gemm1 + (overlapped) maskpack + WT2/WT3
    k_gemm_h<64, 0, 1><<<3348, blk, 0, stream>>>(
        y_atoms, nullptr, WT1, b1, a1, srcp, dstp, hTf,
        y_bonds, maskp, W2, W3, WT2, WT3);
    // node 3
    k_agg<0><<<512, dim3(512), 0, stream>>>(hTf, srcp, dstp, maskp, Ab, nullptr, nullptr);

    // node 4
    k_gemm_h<128, 1, 0><<<1280, blk, 0, stream>>>(
        nullptr, Ab, WT2, b2, a2, srcp, dstp, hTf,
        nullptr, nullptr, nullptr, nullptr, nullptr, nullptr);
    // node 5
    k_agg<0><<<512, dim3(512), 0, stream>>>(hTf, srcp, dstp, maskp, Ab, nullptr, nullptr);

    // node 6
    k_gemm_h<128, 1, 0><<<1280, blk, 0, stream>>>(
        nullptr, Ab, WT3, b3, a3, srcp, dstp, hTf,
        nullptr, nullptr, nullptr, nullptr, nullptr, nullptr);
    // node 7: agg3 + pooling
    k_agg<1><<<512, dim3(512), 0, stream>>>(hTf, srcp, dstp, maskp, nullptr, poolS, poolM);

    // node 8: fused MLP head
    k_tail<<<32, blk, 0, stream>>>(x, poolS, poolM, We1, be1, We2, be2, We3, be3, out);
}

// Round 12
// 201.220 us; speedup vs baseline: 1.7810x; 1.1602x over previous
//
#include <hip/hip_runtime.h>
#include <cstddef>

typedef __attribute__((ext_vector_type(8))) short bf16x8;
typedef __attribute__((ext_vector_type(4))) float f32x4;

__device__ __forceinline__ float lrelu(float x) { return x >= 0.f ? x : 0.2f * x; }
// RNE float -> bf16
__device__ __forceinline__ unsigned short f2bf(float x) {
    unsigned u = __float_as_uint(x);
    u += 0x7FFFu + ((u >> 16) & 1u);
    return (unsigned short)(u >> 16);
}

// =======================================================================================
// k_prepw: WT1 only (the single dependency of gemm1). 10 blocks x 256 threads.
// =======================================================================================
__global__ __launch_bounds__(256) void k_prepw(const float* __restrict__ W1,
                                               unsigned short* __restrict__ WT1) {
    const int nt = blockIdx.x, t = threadIdx.x;
    const int n = nt * 64 + (t & 63);
    for (int kg = t >> 6; kg < 8; kg += 4) {
        bf16x8 v;
#pragma unroll
        for (int e = 0; e < 8; ++e) v[e] = (short)f2bf(W1[(size_t)(kg * 8 + e) * 640 + n]);
        *(bf16x8*)&WT1[(size_t)n * 64 + kg * 8] = v;
    }
}

// =======================================================================================
// gemm_h: round-4 verbatim math. EXTRA=1 (layer-1 node): blocks >= 1280 do maskpack
// (2048 blocks) + WT2/WT3 transposes (20 blocks), overlapped with gemm1 compute;
// consumed only by later nodes -> stream order guarantees visibility.
// gemm blocks: XCD-affinity swizzle, XCD(mt)=mt/16=b/4.
// =======================================================================================
template <int K, int MODE, int EXTRA>
__global__ __launch_bounds__(256) void k_gemm_h(const float* __restrict__ Af32,
                                                const unsigned short* __restrict__ Ab,
                                                const unsigned short* __restrict__ WTg,
                                                const float* __restrict__ bias,
                                                const float* __restrict__ avec,
                                                float* __restrict__ srcp,
                                                float* __restrict__ dstp,
                                                unsigned short* __restrict__ hTf,
                                                const int* __restrict__ bonds,
                                                unsigned char* __restrict__ maskp,
                                                const float* __restrict__ W2,
                                                const float* __restrict__ W3,
                                                unsigned short* __restrict__ WT2,
                                                unsigned short* __restrict__ WT3) {
    const int t = threadIdx.x;
    const int l = blockIdx.x;
    if (EXTRA && l >= 1280) {
        int e = l - 1280;
        if (e < 2048) {
            int gt = e * 256 + t;
            const int4* p = (const int4*)(bonds + (size_t)gt * 20);
            int4 q0 = p[0], q1 = p[1], q2 = p[2], q3 = p[3], q4 = p[4];
            int v[20] = {q0.x, q0.y, q0.z, q0.w, q1.x, q1.y, q1.z, q1.w,
                         q2.x, q2.y, q2.z, q2.w, q3.x, q3.y, q3.z, q3.w,
                         q4.x, q4.y, q4.z, q4.w};
            unsigned m = 0;
#pragma unroll
            for (int k = 0; k < 4; ++k)
#pragma unroll
                for (int r = 0; r < 5; ++r)
                    m |= (v[k * 5 + r] == 1) ? (1u << (k * 8 + r)) : 0u;
            *(unsigned*)&maskp[(size_t)gt * 4] = m;
        } else {
            int e2 = e - 2048;
            const float* W = (e2 < 10) ? W2 : W3;
            unsigned short* WT = (e2 < 10) ? WT2 : WT3;
            int nt = (e2 < 10) ? e2 : e2 - 10;
            int n = nt * 64 + (t & 63);
            for (int kg = t >> 6; kg < 16; kg += 4) {
                bf16x8 v;
#pragma unroll
                for (int ee = 0; ee < 8; ++ee)
                    v[ee] = (short)f2bf(W[(size_t)(kg * 8 + ee) * 640 + n]);
                *(bf16x8*)&WT[(size_t)n * 128 + kg * 8] = v;
            }
        }
        return;
    }
    // bijective swizzle: l = nt*128 + (mt&15)*8 + (mt>>4)
    const int mt = (l & 7) * 16 + ((l >> 3) & 15);   // [0,128)
    const int nt = l >> 7;                            // [0,10)
    const int n0 = nt * 64, m0 = mt * 64;
    const int w = t >> 6, lane = t & 63;
    const int colg = lane & 15, rquad = lane >> 4;
    const int m = m0 + w * 16 + colg;
    const int koff = rquad * 8;

    f32x4 acc[4] = {};
#pragma unroll
    for (int kk = 0; kk < K; kk += 32) {
        bf16x8 af;
        size_t off = (size_t)m * K + kk + koff;
        if (MODE == 1) {
            af = *(const bf16x8*)&Ab[off];
        } else {
            float4 q0 = *(const float4*)&Af32[off];
            float4 q1 = *(const float4*)&Af32[off + 4];
            af[0] = (short)f2bf(q0.x); af[1] = (short)f2bf(q0.y);
            af[2] = (short)f2bf(q0.z); af[3] = (short)f2bf(q0.w);
            af[4] = (short)f2bf(q1.x); af[5] = (short)f2bf(q1.y);
            af[6] = (short)f2bf(q1.z); af[7] = (short)f2bf(q1.w);
        }
#pragma unroll
        for (int ct = 0; ct < 4; ++ct) {
            bf16x8 bfv = *(const bf16x8*)&WTg[(size_t)(n0 + ct * 16 + colg) * K + kk + koff];
            acc[ct] = __builtin_amdgcn_mfma_f32_16x16x32_bf16(af, bfv, acc[ct], 0, 0, 0);
        }
    }

    const int r = n0 >> 7, chalf = n0 & 127;
    const int b = m0 >> 8, jb = m0 & 255;
    float val[4][4];
    float ssum[4] = {0.f, 0.f, 0.f, 0.f}, dsum[4] = {0.f, 0.f, 0.f, 0.f};
#pragma unroll
    for (int ct = 0; ct < 4; ++ct) {
        int cg = chalf + ct * 16 + colg;
        float bv = bias[n0 + ct * 16 + colg];
        float asr = avec[r * 256 + cg];
        float ads = avec[r * 256 + 128 + cg];
#pragma unroll
        for (int reg = 0; reg < 4; ++reg) {
            float v = acc[ct][reg] + bv;
            val[ct][reg] = v;
            ssum[reg] += v * asr;
            dsum[reg] += v * ads;
        }
    }
#pragma unroll
    for (int mk = 1; mk < 16; mk <<= 1)
#pragma unroll
        for (int reg = 0; reg < 4; ++reg) {
            ssum[reg] += __shfl_xor(ssum[reg], mk);
            dsum[reg] += __shfl_xor(dsum[reg], mk);
        }
    if (colg == 0) {
        int nhalf = (n0 >> 6) & 1;
#pragma unroll
        for (int reg = 0; reg < 4; ++reg) {
            int row = m0 + w * 16 + rquad * 4 + reg;
            srcp[nhalf * 40960 + row * 5 + r] = ssum[reg];
            dstp[nhalf * 40960 + row * 5 + r] = dsum[reg];
        }
    }
    {
        const int joct = (jb >> 3) + w * 2 + (rquad >> 1);
        const size_t tile = (size_t)((b * 5 + r) * 32 + joct) * 1024;
        const int sub = (rquad & 1) * 4;
#pragma unroll
        for (int ct = 0; ct < 4; ++ct) {
            int c = chalf + ct * 16 + colg;
            uint2 pk;
            pk.x = (unsigned)f2bf(val[ct][0]) | ((unsigned)f2bf(val[ct][1]) << 16);
            pk.y = (unsigned)f2bf(val[ct][2]) | ((unsigned)f2bf(val[ct][3]) << 16);
            *(uint2*)&hTf[tile + (size_t)c * 8 + sub] = pk;
        }
    }
}

// =======================================================================================
// k_agg: round-4 verbatim. 1-D grid of 512, 512 threads, XCD-affinity swizzle.
// =======================================================================================
template <int FINAL>
__global__ __launch_bounds__(512, 4) void k_agg(const unsigned short* __restrict__ hTf,
                                                const float* __restrict__ srcp,
                                                const float* __restrict__ dstp,
                                                const unsigned char* __restrict__ maskp,
                                                unsigned short* __restrict__ Ab,
                                                float* __restrict__ poolS,
                                                float* __restrict__ poolM) {
    __shared__ __align__(16) unsigned short Ps[20480];
    __shared__ __align__(16) float Ds2l[1280];
    __shared__ float Ss[80], Zw[128], Zrow[16];
    const int t = threadIdx.x;
    const int l = blockIdx.x;
    const int b = (l & 7) * 4 + ((l >> 3) & 3);
    const int itile = l >> 5;
    const int ib = b * 256 + itile * 16;
    const int w = t >> 6, lane = t & 63;
    const int colg = lane & 15, rquad = lane >> 4;
    const int c = w * 16 + colg;
    const size_t bbase = (size_t)(b * 5) * 32 * 1024;

    if (t < 80) Ss[t] = srcp[(size_t)ib * 5 + t] + srcp[40960 + (size_t)ib * 5 + t];
    for (int idx = t; idx < 1280; idx += 512) {
        int jl = idx & 255, rr = idx >> 8;
        size_t o = (size_t)(b * 256 + jl) * 5 + rr;
        Ds2l[rr * 256 + jl] = dstp[o] + dstp[40960 + o];
    }
    bf16x8 pre[4];
#pragma unroll
    for (int s = 0; s < 4; ++s)
        pre[s] = *(const bf16x8*)&hTf[bbase + (size_t)(s * 4 + rquad) * 1024 + (size_t)c * 8];
    __syncthreads();

    {
        const int i = t & 15;
        const int kq = (t >> 4) & 3;
        float esum = 0.f;
#pragma unroll
        for (int it = 0; it < 5; ++it) {
            int p = it * 512 + t;
            int s = p >> 6;
            int k0 = s * 32 + kq * 8;
            int rr = k0 >> 8, j0 = k0 & 255;
            uint2 mk8 = *(const uint2*)&maskp[((size_t)(ib + i) << 8) + j0];
            float sv = Ss[i * 5 + rr];
            float4 d0 = *(const float4*)&Ds2l[rr * 256 + j0];
            float4 d1 = *(const float4*)&Ds2l[rr * 256 + j0 + 4];
            float dv[8] = {d0.x, d0.y, d0.z, d0.w, d1.x, d1.y, d1.z, d1.w};
            bf16x8 pv;
#pragma unroll
            for (int e = 0; e < 8; ++e) {
                unsigned mb = ((e < 4 ? (mk8.x >> (8 * e)) : (mk8.y >> (8 * (e - 4)))) >> rr) & 1u;
                float vv = lrelu(sv + dv[e]);
                float ev = mb ? __expf(vv) : 0.f;
                unsigned short q = f2bf(ev);
                pv[e] = (short)q;
                esum += __uint_as_float((unsigned)q << 16);
            }
            *(bf16x8*)&Ps[p * 8] = pv;
        }
        esum += __shfl_xor(esum, 16);
        esum += __shfl_xor(esum, 32);
        if (lane < 16) Zw[w * 16 + (lane & 15)] = esum;
    }
    __syncthreads();
    if (t < 16) {
        float z = 0.f;
#pragma unroll
        for (int ww = 0; ww < 8; ++ww) z += Zw[ww * 16 + t];
        Zrow[t] = 1.f / z;
    }

    f32x4 acc0 = {}, acc1 = {};
#pragma unroll
    for (int s = 0; s < 8; ++s) {
        bf16x8 af = *(const bf16x8*)&Ps[(s * 64 + lane) * 8];
        bf16x8 bfv;
        if (s < 4) bfv = pre[s];
        else bfv = *(const bf16x8*)&hTf[bbase + (size_t)((s & 7) * 4 + rquad) * 1024 + (size_t)c * 8];
        if (s & 1) acc1 = __builtin_amdgcn_mfma_f32_16x16x32_bf16(af, bfv, acc1, 0, 0, 0);
        else       acc0 = __builtin_amdgcn_mfma_f32_16x16x32_bf16(af, bfv, acc0, 0, 0, 0);
    }
#pragma unroll 8
    for (int s = 8; s < 40; ++s) {
        bf16x8 af = *(const bf16x8*)&Ps[(s * 64 + lane) * 8];
        bf16x8 bfv = *(const bf16x8*)&hTf[bbase +
            (size_t)((s >> 3) * 32 + (s & 7) * 4 + rquad) * 1024 + (size_t)c * 8];
        if (s & 1) acc1 = __builtin_amdgcn_mfma_f32_16x16x32_bf16(af, bfv, acc1, 0, 0, 0);
        else       acc0 = __builtin_amdgcn_mfma_f32_16x16x32_bf16(af, bfv, acc0, 0, 0, 0);
    }
    __syncthreads();
    const int irow = ib + rquad * 4;
    if (FINAL) {
        float ps = 0.f, pm = -3.4e38f;
#pragma unroll
        for (int reg = 0; reg < 4; ++reg) {
            float v = (acc0[reg] + acc1[reg]) * Zrow[rquad * 4 + reg];
            ps += v;
            pm = fmaxf(pm, v);
        }
        ps += __shfl_xor(ps, 16);
        ps += __shfl_xor(ps, 32);
        pm = fmaxf(pm, __shfl_xor(pm, 16));
        pm = fmaxf(pm, __shfl_xor(pm, 32));
        if (rquad == 0) {
            poolS[(size_t)(b * 16 + itile) * 128 + c] = ps;
            poolM[(size_t)(b * 16 + itile) * 128 + c] = pm;
        }
    } else {
#pragma unroll
        for (int reg = 0; reg < 4; ++reg) {
            float v = (acc0[reg] + acc1[reg]) * Zrow[rquad * 4 + reg];
            Ab[(size_t)(irow + reg) * 128 + c] = f2bf(lrelu(v));
        }
    }
}

// =======================================================================================
// k_mlp1: z1 partials (round-4 verbatim — distributed tail, the round-2 fix).
// grid (5 kg, 32 b) = 160 blocks, 256 threads; thread t owns output t.
// =======================================================================================
__global__ __launch_bounds__(256) void k_mlp1(const float* __restrict__ x,
                                              const float* __restrict__ poolS,
                                              const float* __restrict__ poolM,
                                              const float* __restrict__ We1,
                                              float* __restrict__ z1p) {
    const int kg = blockIdx.x, b = blockIdx.y;
    const int t = threadIdx.x;
    __shared__ float zs[256];
    if (kg < 4) {
        zs[t] = x[(size_t)b * 1024 + kg * 256 + t];
    } else if (t < 128) {
        float s = 0.f;
#pragma unroll
        for (int it = 0; it < 16; ++it) s += poolS[(size_t)(b * 16 + it) * 128 + t];
        zs[t] = s * (1.f / 256.f);
    } else {
        int f = t - 128;
        float mx = -3.4e38f;
#pragma unroll
        for (int it = 0; it < 16; ++it) mx = fmaxf(mx, poolM[(size_t)(b * 16 + it) * 128 + f]);
        zs[t] = mx;
    }
    __syncthreads();
    float s = 0.f;
#pragma unroll 8
    for (int k = 0; k < 256; ++k) s += zs[k] * We1[(size_t)(kg * 256 + k) * 256 + t];
    z1p[(size_t)(b * 5 + kg) * 256 + t] = s;
}

// =======================================================================================
// k_mlp2: combine z1 partials + bias + lrelu; mlp2 (k-split 8x32); mlp3 (round-4 verbatim).
// =======================================================================================
__global__ __launch_bounds__(256) void k_mlp2(const float* __restrict__ z1p,
                                              const float* __restrict__ be1,
                                              const float* __restrict__ We2,
                                              const float* __restrict__ be2,
                                              const float* __restrict__ We3,
                                              const float* __restrict__ be3,
                                              float* __restrict__ out) {
    const int b = blockIdx.x, t = threadIdx.x;
    __shared__ float z1s[256];
    __shared__ float s2p[8][32];
    __shared__ float z2s[32];
    {
        float s = be1[t];
#pragma unroll
        for (int kg = 0; kg < 5; ++kg) s += z1p[(size_t)(b * 5 + kg) * 256 + t];
        z1s[t] = lrelu(s);
    }
    __syncthreads();
    {
        int o = t & 31, g = t >> 5;
        float p = 0.f;
#pragma unroll
        for (int k = 0; k < 32; ++k) p += z1s[g * 32 + k] * We2[(g * 32 + k) * 32 + o];
        s2p[g][o] = p;
    }
    __syncthreads();
    if (t < 32) {
        float s2 = be2[t];
#pragma unroll
        for (int g = 0; g < 8; ++g) s2 += s2p[g][t];
        z2s[t] = lrelu(s2);
    }
    __syncthreads();
    if (t == 0) {
        float s3 = be3[0];
#pragma unroll
        for (int k = 0; k < 32; ++k) s3 += z2s[k] * We3[k];
        out[b] = s3;
    }
}

// ---------------- workspace layout ----------------
constexpr size_t O_MASK  = 0;                           // 2,097,152
constexpr size_t O_SRCP  = 2097152;                     // 2 x 40960 floats
constexpr size_t O_DSTP  = O_SRCP + 2ull * 40960 * 4;
constexpr size_t O_AB    = O_DSTP + 2ull * 40960 * 4;   // 8192 x 128 bf16 = 2 MB
constexpr size_t O_HT    = O_AB + 2097152;              // 10.5 MB
constexpr size_t O_WT1   = O_HT + 5242880ull * 2;
constexpr size_t O_WT2   = O_WT1 + 640ull * 64 * 2;
constexpr size_t O_WT3   = O_WT2 + 640ull * 128 * 2;
constexpr size_t O_POOLS = O_WT3 + 640ull * 128 * 2;    // 32 x 16 x 128 fp32
constexpr size_t O_POOLM = O_POOLS + 32ull * 16 * 128 * 4;
constexpr size_t O_Z1P   = O_POOLM + 32ull * 16 * 128 * 4; // 32 x 5 x 256 fp32

extern "C" void kernel_launch(void* const* d_in, const int* in_sizes, int n_in,
                              void* d_out, int out_size, void* d_ws, size_t ws_size,
                              hipStream_t stream) {
    const float* x       = (const float*)d_in[0];
    const float* y_atoms = (const float*)d_in[1];
    const int*   y_bonds = (const int*)d_in[2];
    const float* W1 = (const float*)d_in[3];
    const float* b1 = (const float*)d_in[4];
    const float* a1 = (const float*)d_in[5];
    const float* W2 = (const float*)d_in[6];
    const float* b2 = (const float*)d_in[7];
    const float* a2 = (const float*)d_in[8];
    const float* W3 = (const float*)d_in[9];
    const float* b3 = (const float*)d_in[10];
    const float* a3 = (const float*)d_in[11];
    const float* We1 = (const float*)d_in[12];
    const float* be1 = (const float*)d_in[13];
    const float* We2 = (const float*)d_in[14];
    const float* be2 = (const float*)d_in[15];
    const float* We3 = (const float*)d_in[16];
    const float* be3 = (const float*)d_in[17];
    float* out = (float*)d_out;

    char* ws = (char*)d_ws;
    unsigned char* maskp = (unsigned char*)(ws + O_MASK);
    float* srcp = (float*)(ws + O_SRCP);
    float* dstp = (float*)(ws + O_DSTP);
    unsigned short* Ab = (unsigned short*)(ws + O_AB);
    unsigned short* hTf = (unsigned short*)(ws + O_HT);
    unsigned short* WT1 = (unsigned short*)(ws + O_WT1);
    unsigned short* WT2 = (unsigned short*)(ws + O_WT2);
    unsigned short* WT3 = (unsigned short*)(ws + O_WT3);
    float* poolS = (float*)(ws + O_POOLS);
    float* poolM = (float*)(ws + O_POOLM);
    float* z1p   = (float*)(ws + O_Z1P);

    dim3 blk(256);

    // node 1: WT1 only (gemm1's sole dependency)
    k_prepw<<<10, blk, 0, stream>>>(W1, WT1);

    // node 2: gemm1 + (overlapped) maskpack + WT2/WT3
    k_gemm_h<64, 0, 1><<<3348, blk, 0, stream>>>(
        y_atoms, nullptr, WT1, b1, a1, srcp, dstp, hTf,
        y_bonds, maskp, W2, W3, WT2, WT3);
    // node 3
    k_agg<0><<<512, dim3(512), 0, stream>>>(hTf, srcp, dstp, maskp, Ab, nullptr, nullptr);

    // node 4
    k_gemm_h<128, 1, 0><<<1280, blk, 0, stream>>>(
        nullptr, Ab, WT2, b2, a2, srcp, dstp, hTf,
        nullptr, nullptr, nullptr, nullptr, nullptr, nullptr);
    // node 5
    k_agg<0><<<512, dim3(512), 0, stream>>>(hTf, srcp, dstp, maskp, Ab, nullptr, nullptr);

    // node 6
    k_gemm_h<128, 1, 0><<<1280, blk, 0, stream>>>(
        nullptr, Ab, WT3, b3, a3, srcp, dstp, hTf,
        nullptr, nullptr, nullptr, nullptr, nullptr, nullptr);
    // node 7: agg3 + pooling
    k_agg<1><<<512, dim3(512), 0, stream>>>(hTf, srcp, dstp, maskp, nullptr, poolS, poolM);

    // node 8: distributed mlp1 partials (the round-2 fix — NOT the serial fused tail)
    k_mlp1<<<dim3(5, 32), blk, 0, stream>>>(x, poolS, poolM, We1, z1p);
    // node 9: combine + mlp2 + mlp3
    k_mlp2<<<32, blk, 0, stream>>>(z1p, be1, We2, be2, We3, be3, out);
}